// Round 12
// baseline (4421.525 us; speedup 1.0000x reference)
//
#include <hip/hip_runtime.h>

typedef __bf16 bf16x8 __attribute__((ext_vector_type(8)));
typedef float f32x4 __attribute__((ext_vector_type(4)));
typedef unsigned short us8 __attribute__((ext_vector_type(8)));

typedef __attribute__((address_space(3))) void lds_void_t;
typedef const __attribute__((address_space(1))) void gbl_void_t;

__device__ __forceinline__ unsigned short f2bf(float f) {
    unsigned u = __builtin_bit_cast(unsigned, f);
    u += 0x7FFFu + ((u >> 16) & 1u);   // round-to-nearest-even
    return (unsigned short)(u >> 16);
}
__device__ __forceinline__ float bf2f(unsigned short h) {
    unsigned u = ((unsigned)h) << 16;
    return __builtin_bit_cast(float, u);
}

// ---------------- diagnostic: reveal ws_size via absmax if workspace too small ----
__global__ void report_ws(float* out, float v) { out[0] = v; }

// ---------------- f32 -> bf16 cast (vectorized) ----------------
__global__ __launch_bounds__(256) void cast_bf16(
    const float* __restrict__ src, unsigned short* __restrict__ dst, size_t n8)
{
    size_t i = (size_t)blockIdx.x * 256 + threadIdx.x;
    if (i >= n8) return;
    const float4* s = (const float4*)src + i * 2;
    float4 a = s[0], b = s[1];
    us8 o;
    o[0] = f2bf(a.x); o[1] = f2bf(a.y); o[2] = f2bf(a.z); o[3] = f2bf(a.w);
    o[4] = f2bf(b.x); o[5] = f2bf(b.y); o[6] = f2bf(b.z); o[7] = f2bf(b.w);
    *((us8*)dst + i) = o;
}

// ========== 256x256 bf16 GEMM — single-buffer, 2 blocks/CU (round 12) ==========
// Y = A @ W^T + bias;  A [M,K], W [N,K] bf16 row-major, Y [M,N] bf16.
// 512 threads = 8 waves. BK=64, SINGLE-buffer LDS 64 KiB -> 2 blocks/CU.
// Loop: stage(kt) -> vmcnt(0)+barrier -> pure-dataflow body -> barrier.
// Per-block stage stall is covered by the co-resident block (m114 overlap);
// aggregate demand saturates the LDS/MFMA pipes -> ~2800 cyc/tile target.
// XOR-swizzled LDS (pre-swizzled global src + swizzled ds_read). Epilogue:
// fused bias + deterministic column partials + C staged via LDS in 2 halves.

#define LOAD_AQ(QH) \
  _Pragma("unroll") for (int mm = 0; mm < 4; ++mm) \
    _Pragma("unroll") for (int s = 0; s < 2; ++s) \
      aq[mm][s] = *(const bf16x8*)&lds[aoff + ((QH)*64 + mm*16 + fr)*64 + (((s*4 + fq) ^ w7) << 3)];

#define LOAD_BP(G) \
  _Pragma("unroll") for (int nn = 0; nn < 2; ++nn) \
    _Pragma("unroll") for (int s = 0; s < 2; ++s) \
      bq[(G)*2+nn][s] = *(const bf16x8*)&lds[boff + ((wc&1)*64 + ((G)*2+nn)*16 + fr)*64 + (((s*4 + fq) ^ w7) << 3)];

#define MFMA_QUAD(QH, G) \
  _Pragma("unroll") for (int mm = 0; mm < 4; ++mm) \
    _Pragma("unroll") for (int nn = 0; nn < 2; ++nn) \
      _Pragma("unroll") for (int s = 0; s < 2; ++s) \
        acc[(QH)*4+mm][(G)*2+nn] = __builtin_amdgcn_mfma_f32_16x16x32_bf16( \
            aq[mm][s], bq[(G)*2+nn][s], acc[(QH)*4+mm][(G)*2+nn], 0, 0, 0);

__global__ __launch_bounds__(512, 4) void gemm256(
    const unsigned short* __restrict__ A,
    const unsigned short* __restrict__ W,
    const float* __restrict__ bias,
    unsigned short* __restrict__ Y,
    float* __restrict__ psum, float* __restrict__ psumsq,
    int M, int N, int K, int rowBlkBase)
{
    __shared__ unsigned short lds[32768];   // [op2][half2][8192 elems] = 64 KiB

    const int nbx = N >> 8;
    const int nwg = gridDim.x;
    const int cpx = nwg >> 3;                        // nwg % 8 == 0 guaranteed
    const int bid = blockIdx.x;
    const int swzb = (bid & 7) * cpx + (bid >> 3);   // bijective XCD swizzle
    const int bm = swzb / nbx;
    const int bn = swzb % nbx;

    const int t    = threadIdx.x;
    const int wid  = t >> 6;
    const int lane = t & 63;
    const int wrh  = wid >> 2;        // row half (0/1)
    const int wc   = wid & 3;         // col quarter
    const int fr   = lane & 15;
    const int fq   = lane >> 4;
    const int w7   = fr & 7;

    const int r0s  = t >> 3;                              // staging row 0..63
    const int ce   = (((t & 7) ^ ((t >> 3) & 7)) << 3);   // pre-swizzled col elem

    const size_t baseA = (size_t)(bm << 8) * K;
    const size_t baseW = (size_t)(bn << 8) * K;
    const int NT = K >> 6;

    auto STAGE = [&](int op, int h, int kt) {
        const unsigned short* gsrc = (op ? W : A)
            + (op ? baseW : baseA)
            + (size_t)((h << 7) + r0s) * K + (kt << 6) + ce;
        char* dst = (char*)lds + (((op * 2 + h) << 14) + (wid << 10));
        __builtin_amdgcn_global_load_lds((gbl_void_t*)gsrc, (lds_void_t*)dst, 16, 0, 0);
        __builtin_amdgcn_global_load_lds((gbl_void_t*)(gsrc + (size_t)64 * K),
                                         (lds_void_t*)(dst + 8192), 16, 0, 0);
    };

    const unsigned aoff = (unsigned)wrh * 8192;
    const unsigned boff = (unsigned)(2 + (wc >> 1)) * 8192;

    f32x4 acc[8][4];
#pragma unroll
    for (int m = 0; m < 8; ++m)
#pragma unroll
        for (int n = 0; n < 4; ++n)
            acc[m][n] = (f32x4){0.f, 0.f, 0.f, 0.f};

    bf16x8 aq[4][2], bq[4][2];

    for (int kt = 0; kt < NT; ++kt) {
        // stage tile kt into the single buffer (readers of kt-1 drained by the
        // post-body barrier below)
        STAGE(0, 0, kt); STAGE(0, 1, kt);
        STAGE(1, 0, kt); STAGE(1, 1, kt);
        asm volatile("s_waitcnt vmcnt(0)" ::: "memory");
        __builtin_amdgcn_s_barrier();
        asm volatile("" ::: "memory");   // fence: no LDS reads hoist above barrier

        // pure-dataflow body: compiler inserts fine-grained lgkm waits; the
        // co-resident block computes while this one stages (and vice versa).
        LOAD_AQ(0);
        LOAD_BP(0);
        __builtin_amdgcn_s_setprio(1); MFMA_QUAD(0, 0); __builtin_amdgcn_s_setprio(0);
        LOAD_BP(1);
        __builtin_amdgcn_s_setprio(1); MFMA_QUAD(0, 1); __builtin_amdgcn_s_setprio(0);
        LOAD_AQ(1);
        __builtin_amdgcn_s_setprio(1); MFMA_QUAD(1, 0); MFMA_QUAD(1, 1);
        __builtin_amdgcn_s_setprio(0);

        __builtin_amdgcn_s_barrier();    // all reads of tile kt done
        asm volatile("" ::: "memory");
    }
    __syncthreads();   // drain before LDS reuse in the epilogue

    // ---- epilogue: bias, deterministic column stats, LDS-staged coalesced C ----
    float bv[4];
#pragma unroll
    for (int nn = 0; nn < 4; ++nn) bv[nn] = bias[(bn << 8) + wc * 64 + nn * 16 + fr];

    float* sSum = (float*)lds;             // [256 cols][8 slots] = 8 KiB
    float* sSq  = (float*)lds + 256 * 8;   // 8 KiB
#pragma unroll
    for (int nn = 0; nn < 4; ++nn) {
        float s = 0.f, q = 0.f;
#pragma unroll
        for (int mm = 0; mm < 8; ++mm)
#pragma unroll
            for (int r = 0; r < 4; ++r) {
                float v = acc[mm][nn][r] + bv[nn];
                s += v; q += v * v;
            }
        const int col = wc * 64 + nn * 16 + fr;
        const int sl  = wrh * 4 + fq;
        sSum[col * 8 + sl] = s;
        sSq [col * 8 + sl] = q;
    }
    __syncthreads();
    if (t < 256) {
        float s = 0.f, q = 0.f;
#pragma unroll
        for (int k = 0; k < 8; ++k) { s += sSum[t * 8 + k]; q += sSq[t * 8 + k]; }
        psum  [(size_t)(rowBlkBase + bm) * N + (bn << 8) + t] = s;
        psumsq[(size_t)(rowBlkBase + bm) * N + (bn << 8) + t] = q;
    }
    __syncthreads();

    // C write-out via LDS in two 128-row halves ([128][256] bf16 = 64 KiB)
    const size_t outBase = (size_t)(bm << 8) * N + (bn << 8);
#pragma unroll
    for (int half = 0; half < 2; ++half) {
        if (wrh == half) {
#pragma unroll
            for (int nn = 0; nn < 4; ++nn) {
                const int col = wc * 64 + nn * 16 + fr;
#pragma unroll
                for (int mm = 0; mm < 8; ++mm) {
                    const int row0 = mm * 16 + fq * 4;
#pragma unroll
                    for (int r = 0; r < 4; ++r)
                        lds[(row0 + r) * 256 + col] = f2bf(acc[mm][nn][r] + bv[nn]);
                }
            }
        }
        __syncthreads();
#pragma unroll
        for (int i = 0; i < 8; ++i) {
            const int u   = t + i * 512;        // us8 index within half [0,4096)
            const int row = u >> 5, sl = u & 31;
            us8 v = *(const us8*)&lds[row * 256 + sl * 8];
            *(us8*)&Y[outBase + (size_t)(half * 128 + row) * N + sl * 8] = v;
        }
        __syncthreads();
    }
}

// ---------------- BN stats finalize: reduce row-block partials -> scale/shift ----
__global__ __launch_bounds__(256) void col_stats2(
    const float* __restrict__ psum, const float* __restrict__ psumsq,
    const float* __restrict__ g, const float* __restrict__ be,
    float* __restrict__ scale, float* __restrict__ shift,
    int N, int NB, float invM)
{
    const int col = blockIdx.x * 256 + threadIdx.x;
    float s = 0.f, ss = 0.f;
    for (int c = 0; c < NB; ++c) {
        s  += psum  [(size_t)c * N + col];
        ss += psumsq[(size_t)c * N + col];
    }
    float mu  = s * invM;
    float var = ss * invM - mu * mu;
    float a = g[col] * rsqrtf(var + 1e-5f);
    scale[col] = a;
    shift[col] = be[col] - mu * a;
}

// ---------------- fused normalize + LeakyReLU(0.5) copy (grid-stride) -------------
// src==dst is safe (pure elementwise).
__global__ __launch_bounds__(256) void norm_full(
    const unsigned short* __restrict__ src, unsigned short* __restrict__ dst,
    const float* __restrict__ scale, const float* __restrict__ shift,
    unsigned colMask8, size_t n8)
{
    const size_t stride = (size_t)gridDim.x * 256;
    for (size_t i = (size_t)blockIdx.x * 256 + threadIdx.x; i < n8; i += stride) {
        us8 v = *((const us8*)src + i);
        const unsigned c8 = (unsigned)i & colMask8;
        const float4* sc = (const float4*)scale + c8 * 2;
        const float4* sh = (const float4*)shift + c8 * 2;
        float4 s0 = sc[0], s1 = sc[1], h0 = sh[0], h1 = sh[1];
        float xs[8];
        xs[0] = bf2f(v[0]) * s0.x + h0.x;  xs[1] = bf2f(v[1]) * s0.y + h0.y;
        xs[2] = bf2f(v[2]) * s0.z + h0.z;  xs[3] = bf2f(v[3]) * s0.w + h0.w;
        xs[4] = bf2f(v[4]) * s1.x + h1.x;  xs[5] = bf2f(v[5]) * s1.y + h1.y;
        xs[6] = bf2f(v[6]) * s1.z + h1.z;  xs[7] = bf2f(v[7]) * s1.w + h1.w;
        us8 o;
#pragma unroll
        for (int j = 0; j < 8; ++j) {
            float x = xs[j];
            x = fmaxf(x, 0.5f * x);
            o[j] = f2bf(x);
        }
        *((us8*)dst + i) = o;
    }
}

// ---------------- final matvec with fused norm+leaky on X ----------------
__global__ __launch_bounds__(256) void matvec_norm_out(
    const unsigned short* __restrict__ X, const float* __restrict__ scale,
    const float* __restrict__ shift, const float* __restrict__ wvec,
    const float* __restrict__ bout, float* __restrict__ out, int Kd)
{
    const int row  = blockIdx.x * 4 + (threadIdx.x >> 6);
    const int lane = threadIdx.x & 63;
    const unsigned short* xr = X + (size_t)row * Kd;
    float s = 0.f;
    for (int j = lane * 8; j < Kd; j += 512) {
        us8 x = *(const us8*)(xr + j);
        const float4* sc = (const float4*)(scale + j);
        const float4* sh = (const float4*)(shift + j);
        const float4* wv = (const float4*)(wvec + j);
        float4 s0 = sc[0], s1 = sc[1], h0 = sh[0], h1 = sh[1];
        float4 w0 = wv[0], w1 = wv[1];
        float xs[8] = {
            bf2f(x[0]) * s0.x + h0.x, bf2f(x[1]) * s0.y + h0.y,
            bf2f(x[2]) * s0.z + h0.z, bf2f(x[3]) * s0.w + h0.w,
            bf2f(x[4]) * s1.x + h1.x, bf2f(x[5]) * s1.y + h1.y,
            bf2f(x[6]) * s1.z + h1.z, bf2f(x[7]) * s1.w + h1.w };
        float wf[8] = { w0.x, w0.y, w0.z, w0.w, w1.x, w1.y, w1.z, w1.w };
#pragma unroll
        for (int e = 0; e < 8; ++e) {
            float xv = xs[e];
            xv = fmaxf(xv, 0.5f * xv);
            s += xv * wf[e];
        }
    }
#pragma unroll
    for (int off = 32; off > 0; off >>= 1) s += __shfl_down(s, off);
    if (lane == 0) out[row] = s + bout[0];
}

extern "C" void kernel_launch(void* const* d_in, const int* in_sizes, int n_in,
                              void* d_out, int out_size, void* d_ws, size_t ws_size,
                              hipStream_t stream)
{
    const float* x    = (const float*)d_in[0];
    const float* w1   = (const float*)d_in[1];
    const float* b1   = (const float*)d_in[2];
    const float* g1   = (const float*)d_in[3];
    const float* be1  = (const float*)d_in[4];
    const float* w2   = (const float*)d_in[5];
    const float* b2   = (const float*)d_in[6];
    const float* g2   = (const float*)d_in[7];
    const float* be2  = (const float*)d_in[8];
    const float* w3   = (const float*)d_in[9];
    const float* b3   = (const float*)d_in[10];
    const float* g3   = (const float*)d_in[11];
    const float* be3  = (const float*)d_in[12];
    const float* wout = (const float*)d_in[13];
    const float* bout = (const float*)d_in[14];
    float* out = (float*)d_out;

    const int B = 32768, D = 512, H1 = 2048, H2 = 2048, H3 = 1024;
    const int NB = B / 256;             // 128 row-blocks of partial stats
    const int RCH = 16384;              // row chunk for in-place GEMM2 (2 chunks)
    const float invB = 1.0f / (float)B;
    char* ws = (char*)d_ws;

    size_t off = 0;
    auto alloc = [&](size_t bytes) -> char* {
        char* p = ws + off;
        off += (bytes + 255) & ~(size_t)255;
        return p;
    };
    unsigned short* bufA  = (unsigned short*)alloc((size_t)B * H1 * 2);   // 134.2 MB
    unsigned short* bufY3 = (unsigned short*)alloc((size_t)B * H3 * 2);   //  67.1 MB (Xb / GEMM2 scratch / Y3)
    unsigned short* W1b   = (unsigned short*)alloc((size_t)H1 * D * 2);   //   2.1 MB
    unsigned short* W2b   = (unsigned short*)alloc((size_t)H2 * H1 * 2);  //   8.4 MB
    unsigned short* W3b   = (unsigned short*)alloc((size_t)H3 * H2 * 2);  //   4.2 MB
    float* psum   = (float*)alloc((size_t)NB * H1 * 4);                   //   1.0 MB
    float* psumsq = (float*)alloc((size_t)NB * H1 * 4);                   //   1.0 MB
    float* scale  = (float*)alloc((size_t)H1 * 4);
    float* shift  = (float*)alloc((size_t)H1 * 4);

    if (off > ws_size) {                // ~218 MB; known to fit
        report_ws<<<1, 1, 0, stream>>>(out, (float)ws_size);
        return;
    }

    // --- input casts to bf16 (x lives in bufY3 until GEMM1 consumes it) ---
    {
        size_t n8;
        n8 = (size_t)B * D / 8;   cast_bf16<<<(unsigned)((n8 + 255) / 256), 256, 0, stream>>>(x,  bufY3, n8);
        n8 = (size_t)H1 * D / 8;  cast_bf16<<<(unsigned)((n8 + 255) / 256), 256, 0, stream>>>(w1, W1b, n8);
        n8 = (size_t)H2 * H1 / 8; cast_bf16<<<(unsigned)((n8 + 255) / 256), 256, 0, stream>>>(w2, W2b, n8);
        n8 = (size_t)H3 * H2 / 8; cast_bf16<<<(unsigned)((n8 + 255) / 256), 256, 0, stream>>>(w3, W3b, n8);
    }

    // --- layer 1: Xb @ W1^T -> bufA raw + fused stats ---
    gemm256<<<(B / 256) * (H1 / 256), 512, 0, stream>>>(
        bufY3, W1b, b1, bufA, psum, psumsq, B, H1, D, 0);
    col_stats2<<<H1 / 256, 256, 0, stream>>>(psum, psumsq, g1, be1, scale, shift, H1, NB, invB);

    // --- layer 2: 2 chunks in place on bufA; norm(L1) fused into the chunk copy ---
    const size_t chunk8 = (size_t)RCH * H1 / 8;
    for (int c = 0; c < B / RCH; ++c) {
        norm_full<<<2048, 256, 0, stream>>>(
            bufA + (size_t)c * RCH * H1, bufY3, scale, shift, H1 / 8 - 1, chunk8);
        gemm256<<<(RCH / 256) * (H2 / 256), 512, 0, stream>>>(
            bufY3, W2b, b2, bufA + (size_t)c * RCH * H1, psum, psumsq,
            RCH, H2, H1, c * (RCH / 256));
    }
    col_stats2<<<H2 / 256, 256, 0, stream>>>(psum, psumsq, g2, be2, scale, shift, H2, NB, invB);

    // --- norm(L2) in place, then layer 3 as ONE dispatch ---
    norm_full<<<4096, 256, 0, stream>>>(bufA, bufA, scale, shift, H2 / 8 - 1, (size_t)B * H2 / 8);
    gemm256<<<(B / 256) * (H3 / 256), 512, 0, stream>>>(
        bufA, W3b, b3, bufY3, psum, psumsq, B, H3, H2, 0);
    col_stats2<<<H3 / 256, 256, 0, stream>>>(psum, psumsq, g3, be3, scale, shift, H3, NB, invB);

    // --- output: norm(L3) fused into the matvec ---
    matvec_norm_out<<<B / 4, 256, 0, stream>>>(bufY3, scale, shift, wout, bout, out, H3);
}

// Round 13
// 766.903 us; speedup vs baseline: 5.7654x; 5.7654x over previous
//
#include <hip/hip_runtime.h>

typedef __bf16 bf16x8 __attribute__((ext_vector_type(8)));
typedef float f32x4 __attribute__((ext_vector_type(4)));
typedef unsigned short us8 __attribute__((ext_vector_type(8)));

typedef __attribute__((address_space(3))) void lds_void_t;
typedef const __attribute__((address_space(1))) void gbl_void_t;

__device__ __forceinline__ unsigned short f2bf(float f) {
    unsigned u = __builtin_bit_cast(unsigned, f);
    u += 0x7FFFu + ((u >> 16) & 1u);   // round-to-nearest-even
    return (unsigned short)(u >> 16);
}
__device__ __forceinline__ float bf2f(unsigned short h) {
    unsigned u = ((unsigned)h) << 16;
    return __builtin_bit_cast(float, u);
}

// ---------------- diagnostic: reveal ws_size via absmax if workspace too small ----
__global__ void report_ws(float* out, float v) { out[0] = v; }

// ---------------- f32 -> bf16 cast (vectorized) ----------------
__global__ __launch_bounds__(256) void cast_bf16(
    const float* __restrict__ src, unsigned short* __restrict__ dst, size_t n8)
{
    size_t i = (size_t)blockIdx.x * 256 + threadIdx.x;
    if (i >= n8) return;
    const float4* s = (const float4*)src + i * 2;
    float4 a = s[0], b = s[1];
    us8 o;
    o[0] = f2bf(a.x); o[1] = f2bf(a.y); o[2] = f2bf(a.z); o[3] = f2bf(a.w);
    o[4] = f2bf(b.x); o[5] = f2bf(b.y); o[6] = f2bf(b.z); o[7] = f2bf(b.w);
    *((us8*)dst + i) = o;
}

// ========== 256x256 bf16 GEMM — single-buffer, 2 blocks/CU (round 13) ==========
// Y = A @ W^T + bias;  A [M,K], W [N,K] bf16 row-major, Y [M,N] bf16.
// 512 threads = 8 waves. BK=64, SINGLE-buffer LDS 64 KiB.
// launch_bounds(512, 2): do NOT cap VGPR below need (round-12 lesson: (512,4)
// squeezed to 64 VGPR -> acc spill -> 30x traffic). ~116 VGPR <= 128 satisfies
// the 4-waves/SIMD tier naturally; 64 KiB LDS -> 2 blocks/CU co-resident.
// Loop: stage(kt) -> vmcnt(0)+barrier -> pure-dataflow body -> barrier; the
// co-resident block computes through this block's stage stall (m114 overlap).
// XOR-swizzled LDS. Epilogue: bias + column partials + C staged in 2 halves.

#define LOAD_AQ(QH) \
  _Pragma("unroll") for (int mm = 0; mm < 4; ++mm) \
    _Pragma("unroll") for (int s = 0; s < 2; ++s) \
      aq[mm][s] = *(const bf16x8*)&lds[aoff + ((QH)*64 + mm*16 + fr)*64 + (((s*4 + fq) ^ w7) << 3)];

#define LOAD_BP(G) \
  _Pragma("unroll") for (int nn = 0; nn < 2; ++nn) \
    _Pragma("unroll") for (int s = 0; s < 2; ++s) \
      bq[(G)*2+nn][s] = *(const bf16x8*)&lds[boff + ((wc&1)*64 + ((G)*2+nn)*16 + fr)*64 + (((s*4 + fq) ^ w7) << 3)];

#define MFMA_QUAD(QH, G) \
  _Pragma("unroll") for (int mm = 0; mm < 4; ++mm) \
    _Pragma("unroll") for (int nn = 0; nn < 2; ++nn) \
      _Pragma("unroll") for (int s = 0; s < 2; ++s) \
        acc[(QH)*4+mm][(G)*2+nn] = __builtin_amdgcn_mfma_f32_16x16x32_bf16( \
            aq[mm][s], bq[(G)*2+nn][s], acc[(QH)*4+mm][(G)*2+nn], 0, 0, 0);

__global__ __launch_bounds__(512, 2) void gemm256(
    const unsigned short* __restrict__ A,
    const unsigned short* __restrict__ W,
    const float* __restrict__ bias,
    unsigned short* __restrict__ Y,
    float* __restrict__ psum, float* __restrict__ psumsq,
    int M, int N, int K, int rowBlkBase)
{
    __shared__ unsigned short lds[32768];   // [op2][half2][8192 elems] = 64 KiB

    const int nbx = N >> 8;
    const int nwg = gridDim.x;
    const int cpx = nwg >> 3;                        // nwg % 8 == 0 guaranteed
    const int bid = blockIdx.x;
    const int swzb = (bid & 7) * cpx + (bid >> 3);   // bijective XCD swizzle
    const int bm = swzb / nbx;
    const int bn = swzb % nbx;

    const int t    = threadIdx.x;
    const int wid  = t >> 6;
    const int lane = t & 63;
    const int wrh  = wid >> 2;        // row half (0/1)
    const int wc   = wid & 3;         // col quarter
    const int fr   = lane & 15;
    const int fq   = lane >> 4;
    const int w7   = fr & 7;

    const int r0s  = t >> 3;                              // staging row 0..63
    const int ce   = (((t & 7) ^ ((t >> 3) & 7)) << 3);   // pre-swizzled col elem

    const size_t baseA = (size_t)(bm << 8) * K;
    const size_t baseW = (size_t)(bn << 8) * K;
    const int NT = K >> 6;

    auto STAGE = [&](int op, int h, int kt) {
        const unsigned short* gsrc = (op ? W : A)
            + (op ? baseW : baseA)
            + (size_t)((h << 7) + r0s) * K + (kt << 6) + ce;
        char* dst = (char*)lds + (((op * 2 + h) << 14) + (wid << 10));
        __builtin_amdgcn_global_load_lds((gbl_void_t*)gsrc, (lds_void_t*)dst, 16, 0, 0);
        __builtin_amdgcn_global_load_lds((gbl_void_t*)(gsrc + (size_t)64 * K),
                                         (lds_void_t*)(dst + 8192), 16, 0, 0);
    };

    const unsigned aoff = (unsigned)wrh * 8192;
    const unsigned boff = (unsigned)(2 + (wc >> 1)) * 8192;

    f32x4 acc[8][4];
#pragma unroll
    for (int m = 0; m < 8; ++m)
#pragma unroll
        for (int n = 0; n < 4; ++n)
            acc[m][n] = (f32x4){0.f, 0.f, 0.f, 0.f};

    bf16x8 aq[4][2], bq[4][2];

    for (int kt = 0; kt < NT; ++kt) {
        // stage tile kt into the single buffer (readers of kt-1 drained by the
        // post-body barrier below)
        STAGE(0, 0, kt); STAGE(0, 1, kt);
        STAGE(1, 0, kt); STAGE(1, 1, kt);
        asm volatile("s_waitcnt vmcnt(0)" ::: "memory");
        __builtin_amdgcn_s_barrier();
        asm volatile("" ::: "memory");   // fence: no LDS reads hoist above barrier

        // pure-dataflow body: compiler inserts fine-grained lgkm waits; the
        // co-resident block computes while this one stages (and vice versa).
        LOAD_AQ(0);
        LOAD_BP(0);
        __builtin_amdgcn_s_setprio(1); MFMA_QUAD(0, 0); __builtin_amdgcn_s_setprio(0);
        LOAD_BP(1);
        __builtin_amdgcn_s_setprio(1); MFMA_QUAD(0, 1); __builtin_amdgcn_s_setprio(0);
        LOAD_AQ(1);
        __builtin_amdgcn_s_setprio(1); MFMA_QUAD(1, 0); MFMA_QUAD(1, 1);
        __builtin_amdgcn_s_setprio(0);

        __builtin_amdgcn_s_barrier();    // all reads of tile kt done
        asm volatile("" ::: "memory");
    }
    __syncthreads();   // drain before LDS reuse in the epilogue

    // ---- epilogue: bias, deterministic column stats, LDS-staged coalesced C ----
    float bv[4];
#pragma unroll
    for (int nn = 0; nn < 4; ++nn) bv[nn] = bias[(bn << 8) + wc * 64 + nn * 16 + fr];

    float* sSum = (float*)lds;             // [256 cols][8 slots] = 8 KiB
    float* sSq  = (float*)lds + 256 * 8;   // 8 KiB
#pragma unroll
    for (int nn = 0; nn < 4; ++nn) {
        float s = 0.f, q = 0.f;
#pragma unroll
        for (int mm = 0; mm < 8; ++mm)
#pragma unroll
            for (int r = 0; r < 4; ++r) {
                float v = acc[mm][nn][r] + bv[nn];
                s += v; q += v * v;
            }
        const int col = wc * 64 + nn * 16 + fr;
        const int sl  = wrh * 4 + fq;
        sSum[col * 8 + sl] = s;
        sSq [col * 8 + sl] = q;
    }
    __syncthreads();
    if (t < 256) {
        float s = 0.f, q = 0.f;
#pragma unroll
        for (int k = 0; k < 8; ++k) { s += sSum[t * 8 + k]; q += sSq[t * 8 + k]; }
        psum  [(size_t)(rowBlkBase + bm) * N + (bn << 8) + t] = s;
        psumsq[(size_t)(rowBlkBase + bm) * N + (bn << 8) + t] = q;
    }
    __syncthreads();

    // C write-out via LDS in two 128-row halves ([128][256] bf16 = 64 KiB)
    const size_t outBase = (size_t)(bm << 8) * N + (bn << 8);
#pragma unroll
    for (int half = 0; half < 2; ++half) {
        if (wrh == half) {
#pragma unroll
            for (int nn = 0; nn < 4; ++nn) {
                const int col = wc * 64 + nn * 16 + fr;
#pragma unroll
                for (int mm = 0; mm < 8; ++mm) {
                    const int row0 = mm * 16 + fq * 4;
#pragma unroll
                    for (int r = 0; r < 4; ++r)
                        lds[(row0 + r) * 256 + col] = f2bf(acc[mm][nn][r] + bv[nn]);
                }
            }
        }
        __syncthreads();
#pragma unroll
        for (int i = 0; i < 8; ++i) {
            const int u   = t + i * 512;        // us8 index within half [0,4096)
            const int row = u >> 5, sl = u & 31;
            us8 v = *(const us8*)&lds[row * 256 + sl * 8];
            *(us8*)&Y[outBase + (size_t)(half * 128 + row) * N + sl * 8] = v;
        }
        __syncthreads();
    }
}

// ---------------- BN stats finalize: reduce row-block partials -> scale/shift ----
__global__ __launch_bounds__(256) void col_stats2(
    const float* __restrict__ psum, const float* __restrict__ psumsq,
    const float* __restrict__ g, const float* __restrict__ be,
    float* __restrict__ scale, float* __restrict__ shift,
    int N, int NB, float invM)
{
    const int col = blockIdx.x * 256 + threadIdx.x;
    float s = 0.f, ss = 0.f;
    for (int c = 0; c < NB; ++c) {
        s  += psum  [(size_t)c * N + col];
        ss += psumsq[(size_t)c * N + col];
    }
    float mu  = s * invM;
    float var = ss * invM - mu * mu;
    float a = g[col] * rsqrtf(var + 1e-5f);
    scale[col] = a;
    shift[col] = be[col] - mu * a;
}

// ---------------- fused normalize + LeakyReLU(0.5) copy (grid-stride) -------------
// src==dst is safe (pure elementwise).
__global__ __launch_bounds__(256) void norm_full(
    const unsigned short* __restrict__ src, unsigned short* __restrict__ dst,
    const float* __restrict__ scale, const float* __restrict__ shift,
    unsigned colMask8, size_t n8)
{
    const size_t stride = (size_t)gridDim.x * 256;
    for (size_t i = (size_t)blockIdx.x * 256 + threadIdx.x; i < n8; i += stride) {
        us8 v = *((const us8*)src + i);
        const unsigned c8 = (unsigned)i & colMask8;
        const float4* sc = (const float4*)scale + c8 * 2;
        const float4* sh = (const float4*)shift + c8 * 2;
        float4 s0 = sc[0], s1 = sc[1], h0 = sh[0], h1 = sh[1];
        float xs[8];
        xs[0] = bf2f(v[0]) * s0.x + h0.x;  xs[1] = bf2f(v[1]) * s0.y + h0.y;
        xs[2] = bf2f(v[2]) * s0.z + h0.z;  xs[3] = bf2f(v[3]) * s0.w + h0.w;
        xs[4] = bf2f(v[4]) * s1.x + h1.x;  xs[5] = bf2f(v[5]) * s1.y + h1.y;
        xs[6] = bf2f(v[6]) * s1.z + h1.z;  xs[7] = bf2f(v[7]) * s1.w + h1.w;
        us8 o;
#pragma unroll
        for (int j = 0; j < 8; ++j) {
            float x = xs[j];
            x = fmaxf(x, 0.5f * x);
            o[j] = f2bf(x);
        }
        *((us8*)dst + i) = o;
    }
}

// ---------------- final matvec with fused norm+leaky on X ----------------
__global__ __launch_bounds__(256) void matvec_norm_out(
    const unsigned short* __restrict__ X, const float* __restrict__ scale,
    const float* __restrict__ shift, const float* __restrict__ wvec,
    const float* __restrict__ bout, float* __restrict__ out, int Kd)
{
    const int row  = blockIdx.x * 4 + (threadIdx.x >> 6);
    const int lane = threadIdx.x & 63;
    const unsigned short* xr = X + (size_t)row * Kd;
    float s = 0.f;
    for (int j = lane * 8; j < Kd; j += 512) {
        us8 x = *(const us8*)(xr + j);
        const float4* sc = (const float4*)(scale + j);
        const float4* sh = (const float4*)(shift + j);
        const float4* wv = (const float4*)(wvec + j);
        float4 s0 = sc[0], s1 = sc[1], h0 = sh[0], h1 = sh[1];
        float4 w0 = wv[0], w1 = wv[1];
        float xs[8] = {
            bf2f(x[0]) * s0.x + h0.x, bf2f(x[1]) * s0.y + h0.y,
            bf2f(x[2]) * s0.z + h0.z, bf2f(x[3]) * s0.w + h0.w,
            bf2f(x[4]) * s1.x + h1.x, bf2f(x[5]) * s1.y + h1.y,
            bf2f(x[6]) * s1.z + h1.z, bf2f(x[7]) * s1.w + h1.w };
        float wf[8] = { w0.x, w0.y, w0.z, w0.w, w1.x, w1.y, w1.z, w1.w };
#pragma unroll
        for (int e = 0; e < 8; ++e) {
            float xv = xs[e];
            xv = fmaxf(xv, 0.5f * xv);
            s += xv * wf[e];
        }
    }
#pragma unroll
    for (int off = 32; off > 0; off >>= 1) s += __shfl_down(s, off);
    if (lane == 0) out[row] = s + bout[0];
}

extern "C" void kernel_launch(void* const* d_in, const int* in_sizes, int n_in,
                              void* d_out, int out_size, void* d_ws, size_t ws_size,
                              hipStream_t stream)
{
    const float* x    = (const float*)d_in[0];
    const float* w1   = (const float*)d_in[1];
    const float* b1   = (const float*)d_in[2];
    const float* g1   = (const float*)d_in[3];
    const float* be1  = (const float*)d_in[4];
    const float* w2   = (const float*)d_in[5];
    const float* b2   = (const float*)d_in[6];
    const float* g2   = (const float*)d_in[7];
    const float* be2  = (const float*)d_in[8];
    const float* w3   = (const float*)d_in[9];
    const float* b3   = (const float*)d_in[10];
    const float* g3   = (const float*)d_in[11];
    const float* be3  = (const float*)d_in[12];
    const float* wout = (const float*)d_in[13];
    const float* bout = (const float*)d_in[14];
    float* out = (float*)d_out;

    const int B = 32768, D = 512, H1 = 2048, H2 = 2048, H3 = 1024;
    const int NB = B / 256;             // 128 row-blocks of partial stats
    const int RCH = 16384;              // row chunk for in-place GEMM2 (2 chunks)
    const float invB = 1.0f / (float)B;
    char* ws = (char*)d_ws;

    size_t off = 0;
    auto alloc = [&](size_t bytes) -> char* {
        char* p = ws + off;
        off += (bytes + 255) & ~(size_t)255;
        return p;
    };
    unsigned short* bufA  = (unsigned short*)alloc((size_t)B * H1 * 2);   // 134.2 MB
    unsigned short* bufY3 = (unsigned short*)alloc((size_t)B * H3 * 2);   //  67.1 MB (Xb / GEMM2 scratch / Y3)
    unsigned short* W1b   = (unsigned short*)alloc((size_t)H1 * D * 2);   //   2.1 MB
    unsigned short* W2b   = (unsigned short*)alloc((size_t)H2 * H1 * 2);  //   8.4 MB
    unsigned short* W3b   = (unsigned short*)alloc((size_t)H3 * H2 * 2);  //   4.2 MB
    float* psum   = (float*)alloc((size_t)NB * H1 * 4);                   //   1.0 MB
    float* psumsq = (float*)alloc((size_t)NB * H1 * 4);                   //   1.0 MB
    float* scale  = (float*)alloc((size_t)H1 * 4);
    float* shift  = (float*)alloc((size_t)H1 * 4);

    if (off > ws_size) {                // ~218 MB; known to fit
        report_ws<<<1, 1, 0, stream>>>(out, (float)ws_size);
        return;
    }

    // --- input casts to bf16 (x lives in bufY3 until GEMM1 consumes it) ---
    {
        size_t n8;
        n8 = (size_t)B * D / 8;   cast_bf16<<<(unsigned)((n8 + 255) / 256), 256, 0, stream>>>(x,  bufY3, n8);
        n8 = (size_t)H1 * D / 8;  cast_bf16<<<(unsigned)((n8 + 255) / 256), 256, 0, stream>>>(w1, W1b, n8);
        n8 = (size_t)H2 * H1 / 8; cast_bf16<<<(unsigned)((n8 + 255) / 256), 256, 0, stream>>>(w2, W2b, n8);
        n8 = (size_t)H3 * H2 / 8; cast_bf16<<<(unsigned)((n8 + 255) / 256), 256, 0, stream>>>(w3, W3b, n8);
    }

    // --- layer 1: Xb @ W1^T -> bufA raw + fused stats ---
    gemm256<<<(B / 256) * (H1 / 256), 512, 0, stream>>>(
        bufY3, W1b, b1, bufA, psum, psumsq, B, H1, D, 0);
    col_stats2<<<H1 / 256, 256, 0, stream>>>(psum, psumsq, g1, be1, scale, shift, H1, NB, invB);

    // --- layer 2: 2 chunks in place on bufA; norm(L1) fused into the chunk copy ---
    const size_t chunk8 = (size_t)RCH * H1 / 8;
    for (int c = 0; c < B / RCH; ++c) {
        norm_full<<<2048, 256, 0, stream>>>(
            bufA + (size_t)c * RCH * H1, bufY3, scale, shift, H1 / 8 - 1, chunk8);
        gemm256<<<(RCH / 256) * (H2 / 256), 512, 0, stream>>>(
            bufY3, W2b, b2, bufA + (size_t)c * RCH * H1, psum, psumsq,
            RCH, H2, H1, c * (RCH / 256));
    }
    col_stats2<<<H2 / 256, 256, 0, stream>>>(psum, psumsq, g2, be2, scale, shift, H2, NB, invB);

    // --- norm(L2) in place, then layer 3 as ONE dispatch ---
    norm_full<<<4096, 256, 0, stream>>>(bufA, bufA, scale, shift, H2 / 8 - 1, (size_t)B * H2 / 8);
    gemm256<<<(B / 256) * (H3 / 256), 512, 0, stream>>>(
        bufA, W3b, b3, bufY3, psum, psumsq, B, H3, H2, 0);
    col_stats2<<<H3 / 256, 256, 0, stream>>>(psum, psumsq, g3, be3, scale, shift, H3, NB, invB);

    // --- output: norm(L3) fused into the matvec ---
    matvec_norm_out<<<B / 4, 256, 0, stream>>>(bufY3, scale, shift, wout, bout, out, H3);
}

// Round 15
// 654.836 us; speedup vs baseline: 6.7521x; 1.1711x over previous
//
#include <hip/hip_runtime.h>

typedef __bf16 bf16x8 __attribute__((ext_vector_type(8)));
typedef float f32x4 __attribute__((ext_vector_type(4)));
typedef unsigned short us8 __attribute__((ext_vector_type(8)));

typedef __attribute__((address_space(3))) void lds_void_t;
typedef const __attribute__((address_space(1))) void gbl_void_t;

__device__ __forceinline__ unsigned short f2bf(float f) {
    unsigned u = __builtin_bit_cast(unsigned, f);
    u += 0x7FFFu + ((u >> 16) & 1u);   // round-to-nearest-even
    return (unsigned short)(u >> 16);
}
__device__ __forceinline__ float bf2f(unsigned short h) {
    unsigned u = ((unsigned)h) << 16;
    return __builtin_bit_cast(float, u);
}

// ---------------- diagnostic: reveal ws_size via absmax if workspace too small ----
__global__ void report_ws(float* out, float v) { out[0] = v; }

// ---------------- f32 -> bf16 cast (vectorized) ----------------
__global__ __launch_bounds__(256) void cast_bf16(
    const float* __restrict__ src, unsigned short* __restrict__ dst, size_t n8)
{
    size_t i = (size_t)blockIdx.x * 256 + threadIdx.x;
    if (i >= n8) return;
    const float4* s = (const float4*)src + i * 2;
    float4 a = s[0], b = s[1];
    us8 o;
    o[0] = f2bf(a.x); o[1] = f2bf(a.y); o[2] = f2bf(a.z); o[3] = f2bf(a.w);
    o[4] = f2bf(b.x); o[5] = f2bf(b.y); o[6] = f2bf(b.z); o[7] = f2bf(b.w);
    *((us8*)dst + i) = o;
}

// ================= 256x256 bf16 GEMM — barrier-light K-loop (round-11 best) =======
// Y = A @ W^T + bias;  A [M,K], W [N,K] bf16 row-major, Y [M,N] bf16.
// 512 threads = 8 waves. BK=64, full 2-tile LDS dbuf (128 KiB).
// ONE vmcnt + ONE barrier per K-tile: with full-tile double buffering there are
// no intra-tile LDS hazards — staging(kt+1) targets buf b^1 whose last readers
// (tile kt-1) drained before this tile's barrier; reads of buf b gated by the
// per-wave vmcnt(0) + barrier. Inside the tile: pure dataflow, compiler inserts
// fine-grained lgkm waits; 8 waves skew so LDS pipe overlaps MFMA pipe (TLP).
// Measured: MfmaUtil ~42%, GEMM3 ~143 us. Schedule variants (8-phase, deep
// prefetch, T19 pinning) all plateau at <= this or break — keep verbatim.
// Epilogue: fused bias + deterministic column partials + LDS-staged coalesced C.

#define LOAD_AQ(QH) \
  _Pragma("unroll") for (int mm = 0; mm < 4; ++mm) \
    _Pragma("unroll") for (int s = 0; s < 2; ++s) \
      aq[mm][s] = *(const bf16x8*)&lds[aoff + ((QH)*64 + mm*16 + fr)*64 + (((s*4 + fq) ^ w7) << 3)];

#define LOAD_BP(G) \
  _Pragma("unroll") for (int nn = 0; nn < 2; ++nn) \
    _Pragma("unroll") for (int s = 0; s < 2; ++s) \
      bq[(G)*2+nn][s] = *(const bf16x8*)&lds[boff + ((wc&1)*64 + ((G)*2+nn)*16 + fr)*64 + (((s*4 + fq) ^ w7) << 3)];

#define MFMA_QUAD(QH, G) \
  _Pragma("unroll") for (int mm = 0; mm < 4; ++mm) \
    _Pragma("unroll") for (int nn = 0; nn < 2; ++nn) \
      _Pragma("unroll") for (int s = 0; s < 2; ++s) \
        acc[(QH)*4+mm][(G)*2+nn] = __builtin_amdgcn_mfma_f32_16x16x32_bf16( \
            aq[mm][s], bq[(G)*2+nn][s], acc[(QH)*4+mm][(G)*2+nn], 0, 0, 0);

__global__ __launch_bounds__(512, 2) void gemm256(
    const unsigned short* __restrict__ A,
    const unsigned short* __restrict__ W,
    const float* __restrict__ bias,
    unsigned short* __restrict__ Y,
    float* __restrict__ psum, float* __restrict__ psumsq,
    int M, int N, int K, int rowBlkBase)
{
    __shared__ unsigned short lds[65536];   // [dbuf2][op2][half2][8192 elems] = 128 KiB

    const int nbx = N >> 8;
    const int nwg = gridDim.x;
    const int cpx = nwg >> 3;                        // nwg % 8 == 0 guaranteed
    const int bid = blockIdx.x;
    const int swzb = (bid & 7) * cpx + (bid >> 3);   // bijective XCD swizzle
    const int bm = swzb / nbx;
    const int bn = swzb % nbx;

    const int t    = threadIdx.x;
    const int wid  = t >> 6;
    const int lane = t & 63;
    const int wrh  = wid >> 2;        // row half (0/1)
    const int wc   = wid & 3;         // col quarter
    const int fr   = lane & 15;
    const int fq   = lane >> 4;
    const int w7   = fr & 7;

    const int r0s  = t >> 3;                              // staging row 0..63
    const int ce   = (((t & 7) ^ ((t >> 3) & 7)) << 3);   // pre-swizzled col elem

    const size_t baseA = (size_t)(bm << 8) * K;
    const size_t baseW = (size_t)(bn << 8) * K;
    const int NT = K >> 6;

    auto STAGE = [&](int b, int op, int h, int kt) {
        const unsigned short* gsrc = (op ? W : A)
            + (op ? baseW : baseA)
            + (size_t)((h << 7) + r0s) * K + (kt << 6) + ce;
        char* dst = (char*)lds + ((((b * 2 + op) * 2 + h) << 14) + (wid << 10));
        __builtin_amdgcn_global_load_lds((gbl_void_t*)gsrc, (lds_void_t*)dst, 16, 0, 0);
        __builtin_amdgcn_global_load_lds((gbl_void_t*)(gsrc + (size_t)64 * K),
                                         (lds_void_t*)(dst + 8192), 16, 0, 0);
    };

    f32x4 acc[8][4];
#pragma unroll
    for (int m = 0; m < 8; ++m)
#pragma unroll
        for (int n = 0; n < 4; ++n)
            acc[m][n] = (f32x4){0.f, 0.f, 0.f, 0.f};

    // ---- prologue: stage T0 into buf0 (latency exposed once) ----
    STAGE(0, 0, 0, 0); STAGE(0, 0, 1, 0);
    STAGE(0, 1, 0, 0); STAGE(0, 1, 1, 0);

    bf16x8 aq[4][2], bq[4][2];

    for (int kt = 0; kt < NT; ++kt) {
        const int b = kt & 1;
        const unsigned aoff = (unsigned)(b * 4 + wrh) * 8192;
        const unsigned boff = (unsigned)(b * 4 + 2 + (wc >> 1)) * 8192;

        // tile-boundary sync: my staged slice done (vmcnt) + everyone's (barrier)
        asm volatile("s_waitcnt vmcnt(0)" ::: "memory");
        __builtin_amdgcn_s_barrier();
        asm volatile("" ::: "memory");   // fence: no LDS reads hoist above barrier

        // stage next tile EARLY: a full tile (~2600 cyc) of latency hiding.
        // buf b^1's previous readers (tile kt-1) all drained before this barrier.
        if (kt + 1 < NT) {
            STAGE(b ^ 1, 0, 0, kt + 1); STAGE(b ^ 1, 0, 1, kt + 1);
            STAGE(b ^ 1, 1, 0, kt + 1); STAGE(b ^ 1, 1, 1, kt + 1);
        }

        // pure-dataflow tile body: no barriers, compiler schedules lgkm waits;
        // wave skew overlaps the LDS pipe with the MFMA pipe.
        LOAD_AQ(0);
        LOAD_BP(0);
        __builtin_amdgcn_s_setprio(1); MFMA_QUAD(0, 0); __builtin_amdgcn_s_setprio(0);
        LOAD_BP(1);
        __builtin_amdgcn_s_setprio(1); MFMA_QUAD(0, 1); __builtin_amdgcn_s_setprio(0);
        LOAD_AQ(1);
        __builtin_amdgcn_s_setprio(1); MFMA_QUAD(1, 0); __builtin_amdgcn_s_setprio(0);
        __builtin_amdgcn_s_setprio(1); MFMA_QUAD(1, 1); __builtin_amdgcn_s_setprio(0);
    }
    __syncthreads();   // drain everything before LDS reuse in the epilogue

    // ---- epilogue: bias, deterministic column stats, LDS-staged coalesced C ----
    float bv[4];
#pragma unroll
    for (int nn = 0; nn < 4; ++nn) bv[nn] = bias[(bn << 8) + wc * 64 + nn * 16 + fr];

    float* sSum = (float*)lds;             // [256 cols][8 slots]
    float* sSq  = (float*)lds + 256 * 8;
#pragma unroll
    for (int nn = 0; nn < 4; ++nn) {
        float s = 0.f, q = 0.f;
#pragma unroll
        for (int mm = 0; mm < 8; ++mm)
#pragma unroll
            for (int r = 0; r < 4; ++r) {
                float v = acc[mm][nn][r] + bv[nn];
                s += v; q += v * v;
            }
        const int col = wc * 64 + nn * 16 + fr;
        const int sl  = wrh * 4 + fq;
        sSum[col * 8 + sl] = s;
        sSq [col * 8 + sl] = q;
    }
    __syncthreads();
    if (t < 256) {
        float s = 0.f, q = 0.f;
#pragma unroll
        for (int k = 0; k < 8; ++k) { s += sSum[t * 8 + k]; q += sSq[t * 8 + k]; }
        psum  [(size_t)(rowBlkBase + bm) * N + (bn << 8) + t] = s;
        psumsq[(size_t)(rowBlkBase + bm) * N + (bn << 8) + t] = q;
    }
    __syncthreads();

    // stage C bf16 into dead LDS [256][256], then coalesced us8 write-out
#pragma unroll
    for (int nn = 0; nn < 4; ++nn) {
        const int col = wc * 64 + nn * 16 + fr;
#pragma unroll
        for (int mm = 0; mm < 8; ++mm) {
            const int row0 = wrh * 128 + mm * 16 + fq * 4;
#pragma unroll
            for (int r = 0; r < 4; ++r)
                lds[(row0 + r) * 256 + col] = f2bf(acc[mm][nn][r] + bv[nn]);
        }
    }
    __syncthreads();
    {
        const size_t outBase = (size_t)(bm << 8) * N + (bn << 8);
#pragma unroll
        for (int i = 0; i < 16; ++i) {
            const int u   = t + i * 512;
            const int row = u >> 5, sl = u & 31;
            us8 v = *(const us8*)&lds[row * 256 + sl * 8];
            *(us8*)&Y[outBase + (size_t)row * N + sl * 8] = v;
        }
    }
}

// ---------------- BN stats finalize: reduce row-block partials -> scale/shift ----
__global__ __launch_bounds__(256) void col_stats2(
    const float* __restrict__ psum, const float* __restrict__ psumsq,
    const float* __restrict__ g, const float* __restrict__ be,
    float* __restrict__ scale, float* __restrict__ shift,
    int N, int NB, float invM)
{
    const int col = blockIdx.x * 256 + threadIdx.x;
    float s = 0.f, ss = 0.f;
    for (int c = 0; c < NB; ++c) {
        s  += psum  [(size_t)c * N + col];
        ss += psumsq[(size_t)c * N + col];
    }
    float mu  = s * invM;
    float var = ss * invM - mu * mu;
    float a = g[col] * rsqrtf(var + 1e-5f);
    scale[col] = a;
    shift[col] = be[col] - mu * a;
}

// ---------------- fused normalize + LeakyReLU(0.5) copy (grid-stride) -------------
// src==dst is safe (pure elementwise).
__global__ __launch_bounds__(256) void norm_full(
    const unsigned short* __restrict__ src, unsigned short* __restrict__ dst,
    const float* __restrict__ scale, const float* __restrict__ shift,
    unsigned colMask8, size_t n8)
{
    const size_t stride = (size_t)gridDim.x * 256;
    for (size_t i = (size_t)blockIdx.x * 256 + threadIdx.x; i < n8; i += stride) {
        us8 v = *((const us8*)src + i);
        const unsigned c8 = (unsigned)i & colMask8;
        const float4* sc = (const float4*)scale + c8 * 2;
        const float4* sh = (const float4*)shift + c8 * 2;
        float4 s0 = sc[0], s1 = sc[1], h0 = sh[0], h1 = sh[1];
        float xs[8];
        xs[0] = bf2f(v[0]) * s0.x + h0.x;  xs[1] = bf2f(v[1]) * s0.y + h0.y;
        xs[2] = bf2f(v[2]) * s0.z + h0.z;  xs[3] = bf2f(v[3]) * s0.w + h0.w;
        xs[4] = bf2f(v[4]) * s1.x + h1.x;  xs[5] = bf2f(v[5]) * s1.y + h1.y;
        xs[6] = bf2f(v[6]) * s1.z + h1.z;  xs[7] = bf2f(v[7]) * s1.w + h1.w;
        us8 o;
#pragma unroll
        for (int j = 0; j < 8; ++j) {
            float x = xs[j];
            x = fmaxf(x, 0.5f * x);
            o[j] = f2bf(x);
        }
        *((us8*)dst + i) = o;
    }
}

// ---------------- final matvec with fused norm+leaky on X ----------------
__global__ __launch_bounds__(256) void matvec_norm_out(
    const unsigned short* __restrict__ X, const float* __restrict__ scale,
    const float* __restrict__ shift, const float* __restrict__ wvec,
    const float* __restrict__ bout, float* __restrict__ out, int Kd)
{
    const int row  = blockIdx.x * 4 + (threadIdx.x >> 6);
    const int lane = threadIdx.x & 63;
    const unsigned short* xr = X + (size_t)row * Kd;
    float s = 0.f;
    for (int j = lane * 8; j < Kd; j += 512) {
        us8 x = *(const us8*)(xr + j);
        const float4* sc = (const float4*)(scale + j);
        const float4* sh = (const float4*)(shift + j);
        const float4* wv = (const float4*)(wvec + j);
        float4 s0 = sc[0], s1 = sc[1], h0 = sh[0], h1 = sh[1];
        float4 w0 = wv[0], w1 = wv[1];
        float xs[8] = {
            bf2f(x[0]) * s0.x + h0.x, bf2f(x[1]) * s0.y + h0.y,
            bf2f(x[2]) * s0.z + h0.z, bf2f(x[3]) * s0.w + h0.w,
            bf2f(x[4]) * s1.x + h1.x, bf2f(x[5]) * s1.y + h1.y,
            bf2f(x[6]) * s1.z + h1.z, bf2f(x[7]) * s1.w + h1.w };
        float wf[8] = { w0.x, w0.y, w0.z, w0.w, w1.x, w1.y, w1.z, w1.w };
#pragma unroll
        for (int e = 0; e < 8; ++e) {
            float xv = xs[e];
            xv = fmaxf(xv, 0.5f * xv);
            s += xv * wf[e];
        }
    }
#pragma unroll
    for (int off = 32; off > 0; off >>= 1) s += __shfl_down(s, off);
    if (lane == 0) out[row] = s + bout[0];
}

extern "C" void kernel_launch(void* const* d_in, const int* in_sizes, int n_in,
                              void* d_out, int out_size, void* d_ws, size_t ws_size,
                              hipStream_t stream)
{
    const float* x    = (const float*)d_in[0];
    const float* w1   = (const float*)d_in[1];
    const float* b1   = (const float*)d_in[2];
    const float* g1   = (const float*)d_in[3];
    const float* be1  = (const float*)d_in[4];
    const float* w2   = (const float*)d_in[5];
    const float* b2   = (const float*)d_in[6];
    const float* g2   = (const float*)d_in[7];
    const float* be2  = (const float*)d_in[8];
    const float* w3   = (const float*)d_in[9];
    const float* b3   = (const float*)d_in[10];
    const float* g3   = (const float*)d_in[11];
    const float* be3  = (const float*)d_in[12];
    const float* wout = (const float*)d_in[13];
    const float* bout = (const float*)d_in[14];
    float* out = (float*)d_out;

    const int B = 32768, D = 512, H1 = 2048, H2 = 2048, H3 = 1024;
    const int NB = B / 256;             // 128 row-blocks of partial stats
    const int RCH = 16384;              // row chunk for in-place GEMM2 (2 chunks)
    const float invB = 1.0f / (float)B;
    char* ws = (char*)d_ws;

    size_t off = 0;
    auto alloc = [&](size_t bytes) -> char* {
        char* p = ws + off;
        off += (bytes + 255) & ~(size_t)255;
        return p;
    };
    unsigned short* bufA  = (unsigned short*)alloc((size_t)B * H1 * 2);   // 134.2 MB
    unsigned short* bufY3 = (unsigned short*)alloc((size_t)B * H3 * 2);   //  67.1 MB (Xb / GEMM2 scratch / Y3)
    unsigned short* W1b   = (unsigned short*)alloc((size_t)H1 * D * 2);   //   2.1 MB
    unsigned short* W2b   = (unsigned short*)alloc((size_t)H2 * H1 * 2);  //   8.4 MB
    unsigned short* W3b   = (unsigned short*)alloc((size_t)H3 * H2 * 2);  //   4.2 MB
    float* psum   = (float*)alloc((size_t)NB * H1 * 4);                   //   1.0 MB
    float* psumsq = (float*)alloc((size_t)NB * H1 * 4);                   //   1.0 MB
    float* scale  = (float*)alloc((size_t)H1 * 4);
    float* shift  = (float*)alloc((size_t)H1 * 4);

    if (off > ws_size) {                // ~218 MB; known to fit
        report_ws<<<1, 1, 0, stream>>>(out, (float)ws_size);
        return;
    }

    // --- input casts to bf16 (x lives in bufY3 until GEMM1 consumes it) ---
    {
        size_t n8;
        n8 = (size_t)B * D / 8;   cast_bf16<<<(unsigned)((n8 + 255) / 256), 256, 0, stream>>>(x,  bufY3, n8);
        n8 = (size_t)H1 * D / 8;  cast_bf16<<<(unsigned)((n8 + 255) / 256), 256, 0, stream>>>(w1, W1b, n8);
        n8 = (size_t)H2 * H1 / 8; cast_bf16<<<(unsigned)((n8 + 255) / 256), 256, 0, stream>>>(w2, W2b, n8);
        n8 = (size_t)H3 * H2 / 8; cast_bf16<<<(unsigned)((n8 + 255) / 256), 256, 0, stream>>>(w3, W3b, n8);
    }

    // --- layer 1: Xb @ W1^T -> bufA raw + fused stats ---
    gemm256<<<(B / 256) * (H1 / 256), 512, 0, stream>>>(
        bufY3, W1b, b1, bufA, psum, psumsq, B, H1, D, 0);
    col_stats2<<<H1 / 256, 256, 0, stream>>>(psum, psumsq, g1, be1, scale, shift, H1, NB, invB);

    // --- layer 2: 2 chunks in place on bufA; norm(L1) fused into the chunk copy ---
    const size_t chunk8 = (size_t)RCH * H1 / 8;
    for (int c = 0; c < B / RCH; ++c) {
        norm_full<<<2048, 256, 0, stream>>>(
            bufA + (size_t)c * RCH * H1, bufY3, scale, shift, H1 / 8 - 1, chunk8);
        gemm256<<<(RCH / 256) * (H2 / 256), 512, 0, stream>>>(
            bufY3, W2b, b2, bufA + (size_t)c * RCH * H1, psum, psumsq,
            RCH, H2, H1, c * (RCH / 256));
    }
    col_stats2<<<H2 / 256, 256, 0, stream>>>(psum, psumsq, g2, be2, scale, shift, H2, NB, invB);

    // --- norm(L2) in place, then layer 3 as ONE dispatch ---
    norm_full<<<4096, 256, 0, stream>>>(bufA, bufA, scale, shift, H2 / 8 - 1, (size_t)B * H2 / 8);
    gemm256<<<(B / 256) * (H3 / 256), 512, 0, stream>>>(
        bufA, W3b, b3, bufY3, psum, psumsq, B, H3, H2, 0);
    col_stats2<<<H3 / 256, 256, 0, stream>>>(psum, psumsq, g3, be3, scale, shift, H3, NB, invB);

    // --- output: norm(L3) fused into the matvec ---
    matvec_norm_out<<<B / 4, 256, 0, stream>>>(bufY3, scale, shift, wout, bout, out, H3);
}